// Round 9
// baseline (260.965 us; speedup 1.0000x reference)
//
#include <hip/hip_runtime.h>

#define BS 2
#define SEQ 2048
#define HID 1024
#define HEADS 16
#define HDIM 64
#define MTOT (BS * SEQ)  // 4096

typedef __bf16 bf16x8 __attribute__((ext_vector_type(8)));
typedef float floatx4 __attribute__((ext_vector_type(4)));
typedef short short8 __attribute__((ext_vector_type(8)));
typedef unsigned short u16x4 __attribute__((ext_vector_type(4)));
typedef unsigned int u32x2 __attribute__((ext_vector_type(2)));

__device__ __forceinline__ floatx4 mfma16x16x32bf16(short8 a, short8 b, floatx4 c) {
    return __builtin_amdgcn_mfma_f32_16x16x32_bf16(
        __builtin_bit_cast(bf16x8, a), __builtin_bit_cast(bf16x8, b), c, 0, 0, 0);
}

__device__ __forceinline__ unsigned short f2bf(float f) {
    unsigned int u = __builtin_bit_cast(unsigned int, f);
    u += 0x7fffu + ((u >> 16) & 1u);   // RNE
    return (unsigned short)(u >> 16);
}

#define GLOAD_LDS16(gsrc, ldst)                                                   \
    __builtin_amdgcn_global_load_lds(                                             \
        (const __attribute__((address_space(1))) void*)(gsrc),                    \
        (__attribute__((address_space(3))) void*)(ldst), 16, 0, 0)

// fp32 -> bf16 conversion: X (4M) + Wq,Wk,Wv,Wo (1M each).
// Wq (y==1) is pre-scaled by 1/sqrt(HDIM)=0.125 so attention needs no scale.
__global__ __launch_bounds__(256) void cvt5(
    const float* __restrict__ X, const float* __restrict__ Wq,
    const float* __restrict__ Wk, const float* __restrict__ Wv,
    const float* __restrict__ Wo, unsigned short* __restrict__ dst)
{
    const int y = blockIdx.y;
    const float* src = (y == 0) ? X : (y == 1) ? Wq : (y == 2) ? Wk : (y == 3) ? Wv : Wo;
    const size_t base = (y == 0) ? 0 : (size_t)(4u << 20) + (size_t)(y - 1) * (1u << 20);
    const int n4 = (y == 0) ? (1 << 20) : (1 << 18);
    const float scale = (y == 1) ? 0.125f : 1.0f;
    int i = blockIdx.x * 256 + threadIdx.x;
    if (i >= n4) return;
    floatx4 v = *(const floatx4*)(src + (size_t)i * 4);
    v *= scale;
    unsigned int p0 = (unsigned int)f2bf(v[0]) | ((unsigned int)f2bf(v[1]) << 16);
    unsigned int p1 = (unsigned int)f2bf(v[2]) | ((unsigned int)f2bf(v[3]) << 16);
    u32x2 pk = {p0, p1};
    *(u32x2*)(dst + base + (size_t)i * 4) = pk;
}

// C = X @ W^T + bias, m97 structure (128x128, BK=32, global_load_lds w=16).
// MODE 0: fp32 out row-major [m][n] (out-projection).
// MODE 1: QKV.  z<2 (Q,K): operand-swapped MFMA -> D[n][m]; lane packs 4
//   consecutive d -> 8B bf16 stores at [b][h][s][d], out offset z*T.
//   z==0 bias scaled by 0.125 (matches pre-scaled Wq).
//   z==2 (V): normal MFMA; 8B stores at 2*T + [b][h][d][s] (V^T).
template <int MODE>
__global__ __launch_bounds__(256) void gemm_bt(
    const unsigned short* __restrict__ X,
    const unsigned short* __restrict__ W0, const unsigned short* __restrict__ W1,
    const unsigned short* __restrict__ W2,
    const float* __restrict__ B0, const float* __restrict__ B1,
    const float* __restrict__ B2,
    unsigned short* __restrict__ out_bf, float* __restrict__ out_f)
{
    __shared__ __align__(16) unsigned short sA[128 * 32];
    __shared__ __align__(16) unsigned short sB[128 * 32];

    const int tid  = threadIdx.x;
    const int z    = blockIdx.z;
    const unsigned short* W  = (z == 0) ? W0 : (z == 1) ? W1 : W2;
    const float*          Bb = (z == 0) ? B0 : (z == 1) ? B1 : B2;
    const float bscale = (MODE == 1 && z == 0) ? 0.125f : 1.0f;
    const int m0   = blockIdx.x * 128;
    const int n0   = blockIdx.y * 128;
    const int lane = tid & 63, w = tid >> 6;
    const int l16  = lane & 15, grp = lane >> 4;
    const int wm   = w & 1, wn = w >> 1;

    floatx4 acc[4][4];
#pragma unroll
    for (int i = 0; i < 4; ++i)
#pragma unroll
        for (int j = 0; j < 4; ++j) acc[i][j] = (floatx4){0.f, 0.f, 0.f, 0.f};

    auto stage = [&](int kb) {
        const int kcol = kb * 32;
#pragma unroll
        for (int i = 0; i < 2; ++i) {
            int g = tid + i * 256;
            int row = g >> 2, c8 = (g & 3) * 8;
            GLOAD_LDS16(X + (size_t)(m0 + row) * HID + kcol + c8, &sA[g * 8]);
            GLOAD_LDS16(W + (size_t)(n0 + row) * HID + kcol + c8, &sB[g * 8]);
        }
    };

    const bool swapT = (MODE == 1) && (z < 2);
    stage(0);
    for (int kb = 0; kb < 32; ++kb) {
        __syncthreads();
        short8 af[4], bfr[4];
#pragma unroll
        for (int t = 0; t < 4; ++t) {
            af[t]  = *(const short8*)&sA[(wm * 64 + t * 16 + l16) * 32 + grp * 8];
            bfr[t] = *(const short8*)&sB[(wn * 64 + t * 16 + l16) * 32 + grp * 8];
        }
        __syncthreads();
        if (kb + 1 < 32) stage(kb + 1);
        if (swapT) {
#pragma unroll
            for (int mt = 0; mt < 4; ++mt)
#pragma unroll
                for (int nt = 0; nt < 4; ++nt)
                    acc[mt][nt] = mfma16x16x32bf16(bfr[nt], af[mt], acc[mt][nt]);
        } else {
#pragma unroll
            for (int mt = 0; mt < 4; ++mt)
#pragma unroll
                for (int nt = 0; nt < 4; ++nt)
                    acc[mt][nt] = mfma16x16x32bf16(af[mt], bfr[nt], acc[mt][nt]);
        }
    }

    if (MODE == 0) {
        // D[row=m: grp*4+r][col=n: l16] (m89-verified) -> fp32 [m][n]
#pragma unroll
        for (int nt = 0; nt < 4; ++nt) {
            int n = n0 + wn * 64 + nt * 16 + l16;
            float bias = Bb[n];
#pragma unroll
            for (int mt = 0; mt < 4; ++mt)
#pragma unroll
                for (int r = 0; r < 4; ++r) {
                    int m = m0 + wm * 64 + mt * 16 + grp * 4 + r;
                    out_f[(size_t)m * HID + n] = acc[mt][nt][r] + bias;
                }
        }
    } else if (z < 2) {
        // swapped: D[row=n: grp*4+r][col=m: l16] -> bf16 [b][h][s][d], 8B packed
        const size_t outz = (size_t)z * ((size_t)MTOT * HID);
        const int hidx = (n0 + wn * 64) >> 6;
#pragma unroll
        for (int nt = 0; nt < 4; ++nt) {
            int dbase = nt * 16 + grp * 4;
            floatx4 b4 = *(const floatx4*)&Bb[n0 + wn * 64 + dbase];
            b4 *= bscale;
#pragma unroll
            for (int mt = 0; mt < 4; ++mt) {
                int m = m0 + wm * 64 + mt * 16 + l16;
                int bidx = m >> 11, s = m & (SEQ - 1);
                u16x4 pk;
#pragma unroll
                for (int r = 0; r < 4; ++r) pk[r] = f2bf(acc[mt][nt][r] + b4[r]);
                *(u16x4*)&out_bf[outz +
                    ((((size_t)bidx * HEADS + hidx) * SEQ + s) * HDIM + dbase)] = pk;
            }
        }
    } else {
        // normal: D[row=m(s): grp*4+r][col=n(d): l16] -> bf16 V^T [b][h][d][s] at 2*T
        const size_t outz = (size_t)2 * ((size_t)MTOT * HID);
        const int hidx = (n0 + wn * 64) >> 6;
#pragma unroll
        for (int nt = 0; nt < 4; ++nt) {
            int d = nt * 16 + l16;
            float bias = Bb[n0 + wn * 64 + d];
#pragma unroll
            for (int mt = 0; mt < 4; ++mt) {
                int mbase = m0 + wm * 64 + mt * 16 + grp * 4;
                int bidx = mbase >> 11, sbase = mbase & (SEQ - 1);
                u16x4 pk;
#pragma unroll
                for (int r = 0; r < 4; ++r) pk[r] = f2bf(acc[mt][nt][r] + bias);
                *(u16x4*)&out_bf[outz +
                    ((((size_t)bidx * HEADS + hidx) * HDIM + d) * SEQ + sbase)] = pk;
            }
        }
    }
}

// Barrier-free flash attention, SINGLE-WAVE workgroups (64 thr).
// Grid: 2048 flat.  id -> (b,h) pinned to one XCD via id%8 (L2 locality);
// within (b,h): qb DESCENDING (longest workgroups dispatch first), qhalf in bit0.
// Wave owns 32 q-rows; frags straight from global; P via wave-private LDS.
// Q,K: [b][h][s][d] (Q pre-scaled by 1/8); V: [b][h][d][s].
__global__ __launch_bounds__(64) void attn_kernel(
    const unsigned short* __restrict__ Qw, const unsigned short* __restrict__ Kw,
    const unsigned short* __restrict__ VTw, unsigned short* __restrict__ X2)
{
    __shared__ __align__(16) unsigned short Ps[32][72];   // 4.6 KB, wave-private

    const int id = blockIdx.x;                 // 0..2047
    const int xcd = id & 7, k = id >> 3;       // k: 0..255
    const int bh  = (k >> 6) * 8 + xcd;        // 0..31, fixed id%8 per bh
    const int k2  = k & 63;
    const int qblk = 31 - (k2 >> 1);           // descending
    const int qhalf = k2 & 1;
    const int b = bh >> 4, h = bh & 15;

    const int tid  = threadIdx.x;
    const int lane = tid & 63;
    const int l16  = lane & 15, grp = lane >> 4;

    const int nkb = qblk + 1;
    const int q0  = qblk * 64 + qhalf * 32;

    const size_t head = ((size_t)b * HEADS + h) * (size_t)SEQ * HDIM;

    short8 qf[2][2];   // [mt][ks] A-frags, loaded once
#pragma unroll
    for (int mt = 0; mt < 2; ++mt)
#pragma unroll
        for (int ks = 0; ks < 2; ++ks)
            qf[mt][ks] = *(const short8*)(Qw + head +
                (size_t)(q0 + mt * 16 + l16) * HDIM + ks * 32 + grp * 8);

    floatx4 o[2][4];
    float mi[2][4], li[2][4];
#pragma unroll
    for (int mt = 0; mt < 2; ++mt)
#pragma unroll
        for (int i = 0; i < 4; ++i) {
            o[mt][i] = (floatx4){0.f, 0.f, 0.f, 0.f};
            mi[mt][i] = -1e30f; li[mt][i] = 0.f;
        }

    for (int kb = 0; kb < nkb; ++kb) {
        const unsigned short* kbase = Kw + head + (size_t)kb * 64 * HDIM;
        const unsigned short* vbase = VTw + head + (size_t)kb * 64;
        short8 kf[4][2], vf[4][2];
#pragma unroll
        for (int nt = 0; nt < 4; ++nt)
#pragma unroll
            for (int ks = 0; ks < 2; ++ks) {
                kf[nt][ks] = *(const short8*)(kbase +
                    (size_t)(nt * 16 + l16) * HDIM + ks * 32 + grp * 8);
                vf[nt][ks] = *(const short8*)(vbase +
                    (size_t)(nt * 16 + l16) * SEQ + ks * 32 + grp * 8);
            }

        floatx4 sv[2][4];
#pragma unroll
        for (int mt = 0; mt < 2; ++mt)
#pragma unroll
            for (int nt = 0; nt < 4; ++nt) {
                floatx4 zz = (floatx4){0.f, 0.f, 0.f, 0.f};
                zz = mfma16x16x32bf16(qf[mt][0], kf[nt][0], zz);
                zz = mfma16x16x32bf16(qf[mt][1], kf[nt][1], zz);
                sv[mt][nt] = zz;               // scale folded into Q
            }

#pragma unroll
        for (int mt = 0; mt < 2; ++mt) {
            float alpha[4];
#pragma unroll
            for (int r = 0; r < 4; ++r) {
                float mx = fmaxf(fmaxf(sv[mt][0][r], sv[mt][1][r]),
                                 fmaxf(sv[mt][2][r], sv[mt][3][r]));
#pragma unroll
                for (int off = 1; off < 16; off <<= 1)
                    mx = fmaxf(mx, __shfl_xor(mx, off, 16));
                float mn = fmaxf(mi[mt][r], mx);
                alpha[r] = __expf(mi[mt][r] - mn);
                mi[mt][r] = mn;
                float rs = 0.f;
#pragma unroll
                for (int nt = 0; nt < 4; ++nt) {
                    float p = __expf(sv[mt][nt][r] - mn);
                    sv[mt][nt][r] = p;
                    rs += p;
                }
#pragma unroll
                for (int off = 1; off < 16; off <<= 1)
                    rs += __shfl_xor(rs, off, 16);
                li[mt][r] = li[mt][r] * alpha[r] + rs;
            }
#pragma unroll
            for (int nt = 0; nt < 4; ++nt)
#pragma unroll
                for (int r = 0; r < 4; ++r)
                    Ps[mt * 16 + grp * 4 + r][nt * 16 + l16] = f2bf(sv[mt][nt][r]);
#pragma unroll
            for (int dt = 0; dt < 4; ++dt)
#pragma unroll
                for (int r = 0; r < 4; ++r) o[mt][dt][r] *= alpha[r];
        }

        // wave-private round-trip: same-wave DS ordering + lgkmcnt suffices
#pragma unroll
        for (int ks = 0; ks < 2; ++ks)
#pragma unroll
            for (int mt = 0; mt < 2; ++mt) {
                short8 pf = *(const short8*)&Ps[mt * 16 + l16][ks * 32 + grp * 8];
#pragma unroll
                for (int dt = 0; dt < 4; ++dt)
                    o[mt][dt] = mfma16x16x32bf16(pf, vf[dt][ks], o[mt][dt]);
            }
    }

    // O / l  ->  X2 [b][s][h*64+d]
#pragma unroll
    for (int mt = 0; mt < 2; ++mt) {
        float inv[4];
#pragma unroll
        for (int r = 0; r < 4; ++r) inv[r] = 1.0f / li[mt][r];
#pragma unroll
        for (int dt = 0; dt < 4; ++dt)
#pragma unroll
            for (int r = 0; r < 4; ++r) {
                int srow = q0 + mt * 16 + grp * 4 + r;
                int col  = h * HDIM + dt * 16 + l16;
                X2[((size_t)b * SEQ + srow) * HID + col] = f2bf(o[mt][dt][r] * inv[r]);
            }
    }
}

extern "C" void kernel_launch(void* const* d_in, const int* in_sizes, int n_in,
                              void* d_out, int out_size, void* d_ws, size_t ws_size,
                              hipStream_t stream) {
    // dict order confirmed (R5/R6); alphabetical fallback kept as safety net
    int iX, iWq, ibq, iWk, ibk, iWv, ibv, iWo, ibo;
    if (in_sizes[0] == MTOT * HID) {
        iX = 0; iWq = 1; ibq = 2; iWk = 3; ibk = 4; iWv = 5; ibv = 6; iWo = 7; ibo = 8;
    } else {
        iWk = 0; iWo = 1; iWq = 2; iWv = 3; ibk = 4; ibo = 5; ibq = 6; ibv = 7; iX = 8;
    }
    const float* X  = (const float*)d_in[iX];
    const float* Wq = (const float*)d_in[iWq];
    const float* bq = (const float*)d_in[ibq];
    const float* Wk = (const float*)d_in[iWk];
    const float* bk = (const float*)d_in[ibk];
    const float* Wv = (const float*)d_in[iWv];
    const float* bv = (const float*)d_in[ibv];
    const float* Wo = (const float*)d_in[iWo];
    const float* bo = (const float*)d_in[ibo];
    float* out = (float*)d_out;                // fp32 output (confirmed R6)

    unsigned short* ws = (unsigned short*)d_ws;
    const size_t T = (size_t)MTOT * HID;       // 4M elements
    unsigned short* qw  = ws;                  // Q  [b][h][s][d], pre-scaled 1/8
    unsigned short* kw  = ws + T;              // K  [b][h][s][d]
    unsigned short* vtw = ws + 2 * T;          // V^T[b][h][d][s]
    unsigned short* x2  = ws + 3 * T;          // attn out [b][s][hid]
    unsigned short* Xb  = ws + 4 * T;
    unsigned short* Wqb = Xb + T;
    unsigned short* Wkb = Wqb + (size_t)HID * HID;
    unsigned short* Wvb = Wkb + (size_t)HID * HID;
    unsigned short* Wob = Wvb + (size_t)HID * HID;

    // 0) fp32 -> bf16 (Wq pre-scaled by 0.125)
    cvt5<<<dim3(4096, 5), 256, 0, stream>>>(X, Wq, Wk, Wv, Wo, Xb);
    // 1) QKV projections: z=0 Q (scaled), z=1 K (swapped epilogue), z=2 V^T
    gemm_bt<1><<<dim3(32, 8, 3), 256, 0, stream>>>(
        Xb, Wqb, Wkb, Wvb, bq, bk, bv, qw, nullptr);
    // 2) barrier-free flash attention, single-wave workgroups, XCD-pinned
    attn_kernel<<<dim3(2048), 64, 0, stream>>>(qw, kw, vtw, x2);
    // 3) output projection -> d_out (fp32)
    gemm_bt<0><<<dim3(32, 8, 1), 256, 0, stream>>>(
        x2, Wob, Wob, Wob, bo, bo, bo, nullptr, out);
}

// Round 10
// 242.772 us; speedup vs baseline: 1.0749x; 1.0749x over previous
//
#include <hip/hip_runtime.h>

#define BS 2
#define SEQ 2048
#define HID 1024
#define HEADS 16
#define HDIM 64
#define MTOT (BS * SEQ)  // 4096

typedef __bf16 bf16x8 __attribute__((ext_vector_type(8)));
typedef float floatx4 __attribute__((ext_vector_type(4)));
typedef short short8 __attribute__((ext_vector_type(8)));
typedef unsigned short u16x4 __attribute__((ext_vector_type(4)));
typedef unsigned int u32x2 __attribute__((ext_vector_type(2)));

__device__ __forceinline__ floatx4 mfma16x16x32bf16(short8 a, short8 b, floatx4 c) {
    return __builtin_amdgcn_mfma_f32_16x16x32_bf16(
        __builtin_bit_cast(bf16x8, a), __builtin_bit_cast(bf16x8, b), c, 0, 0, 0);
}

__device__ __forceinline__ unsigned short f2bf(float f) {
    unsigned int u = __builtin_bit_cast(unsigned int, f);
    u += 0x7fffu + ((u >> 16) & 1u);   // RNE
    return (unsigned short)(u >> 16);
}

#define GLOAD_LDS16(gsrc, ldst)                                                   \
    __builtin_amdgcn_global_load_lds(                                             \
        (const __attribute__((address_space(1))) void*)(gsrc),                    \
        (__attribute__((address_space(3))) void*)(ldst), 16, 0, 0)

// fp32 -> bf16 conversion: X (4M) + Wq,Wk,Wv,Wo (1M each).  Wq pre-scaled 1/8.
__global__ __launch_bounds__(256) void cvt5(
    const float* __restrict__ X, const float* __restrict__ Wq,
    const float* __restrict__ Wk, const float* __restrict__ Wv,
    const float* __restrict__ Wo, unsigned short* __restrict__ dst)
{
    const int y = blockIdx.y;
    const float* src = (y == 0) ? X : (y == 1) ? Wq : (y == 2) ? Wk : (y == 3) ? Wv : Wo;
    const size_t base = (y == 0) ? 0 : (size_t)(4u << 20) + (size_t)(y - 1) * (1u << 20);
    const int n4 = (y == 0) ? (1 << 20) : (1 << 18);
    const float scale = (y == 1) ? 0.125f : 1.0f;
    int i = blockIdx.x * 256 + threadIdx.x;
    if (i >= n4) return;
    floatx4 v = *(const floatx4*)(src + (size_t)i * 4);
    v *= scale;
    unsigned int p0 = (unsigned int)f2bf(v[0]) | ((unsigned int)f2bf(v[1]) << 16);
    unsigned int p1 = (unsigned int)f2bf(v[2]) | ((unsigned int)f2bf(v[3]) << 16);
    u32x2 pk = {p0, p1};
    *(u32x2*)(dst + base + (size_t)i * 4) = pk;
}

// C = X @ W^T + bias, m97 structure.  MODE 0: fp32 [m][n].  MODE 1: QKV
// (z<2 swapped epilogue -> [b][h][s][d] packed; z==2 -> V^T [b][h][d][s] at 2T).
template <int MODE>
__global__ __launch_bounds__(256) void gemm_bt(
    const unsigned short* __restrict__ X,
    const unsigned short* __restrict__ W0, const unsigned short* __restrict__ W1,
    const unsigned short* __restrict__ W2,
    const float* __restrict__ B0, const float* __restrict__ B1,
    const float* __restrict__ B2,
    unsigned short* __restrict__ out_bf, float* __restrict__ out_f)
{
    __shared__ __align__(16) unsigned short sA[128 * 32];
    __shared__ __align__(16) unsigned short sB[128 * 32];

    const int tid  = threadIdx.x;
    const int z    = blockIdx.z;
    const unsigned short* W  = (z == 0) ? W0 : (z == 1) ? W1 : W2;
    const float*          Bb = (z == 0) ? B0 : (z == 1) ? B1 : B2;
    const float bscale = (MODE == 1 && z == 0) ? 0.125f : 1.0f;
    const int m0   = blockIdx.x * 128;
    const int n0   = blockIdx.y * 128;
    const int lane = tid & 63, w = tid >> 6;
    const int l16  = lane & 15, grp = lane >> 4;
    const int wm   = w & 1, wn = w >> 1;

    floatx4 acc[4][4];
#pragma unroll
    for (int i = 0; i < 4; ++i)
#pragma unroll
        for (int j = 0; j < 4; ++j) acc[i][j] = (floatx4){0.f, 0.f, 0.f, 0.f};

    auto stage = [&](int kb) {
        const int kcol = kb * 32;
#pragma unroll
        for (int i = 0; i < 2; ++i) {
            int g = tid + i * 256;
            int row = g >> 2, c8 = (g & 3) * 8;
            GLOAD_LDS16(X + (size_t)(m0 + row) * HID + kcol + c8, &sA[g * 8]);
            GLOAD_LDS16(W + (size_t)(n0 + row) * HID + kcol + c8, &sB[g * 8]);
        }
    };

    const bool swapT = (MODE == 1) && (z < 2);
    stage(0);
    for (int kb = 0; kb < 32; ++kb) {
        __syncthreads();
        short8 af[4], bfr[4];
#pragma unroll
        for (int t = 0; t < 4; ++t) {
            af[t]  = *(const short8*)&sA[(wm * 64 + t * 16 + l16) * 32 + grp * 8];
            bfr[t] = *(const short8*)&sB[(wn * 64 + t * 16 + l16) * 32 + grp * 8];
        }
        __syncthreads();
        if (kb + 1 < 32) stage(kb + 1);
        if (swapT) {
#pragma unroll
            for (int mt = 0; mt < 4; ++mt)
#pragma unroll
                for (int nt = 0; nt < 4; ++nt)
                    acc[mt][nt] = mfma16x16x32bf16(bfr[nt], af[mt], acc[mt][nt]);
        } else {
#pragma unroll
            for (int mt = 0; mt < 4; ++mt)
#pragma unroll
                for (int nt = 0; nt < 4; ++nt)
                    acc[mt][nt] = mfma16x16x32bf16(af[mt], bfr[nt], acc[mt][nt]);
        }
    }

    if (MODE == 0) {
#pragma unroll
        for (int nt = 0; nt < 4; ++nt) {
            int n = n0 + wn * 64 + nt * 16 + l16;
            float bias = Bb[n];
#pragma unroll
            for (int mt = 0; mt < 4; ++mt)
#pragma unroll
                for (int r = 0; r < 4; ++r) {
                    int m = m0 + wm * 64 + mt * 16 + grp * 4 + r;
                    out_f[(size_t)m * HID + n] = acc[mt][nt][r] + bias;
                }
        }
    } else if (z < 2) {
        const size_t outz = (size_t)z * ((size_t)MTOT * HID);
        const int hidx = (n0 + wn * 64) >> 6;
#pragma unroll
        for (int nt = 0; nt < 4; ++nt) {
            int dbase = nt * 16 + grp * 4;
            floatx4 b4 = *(const floatx4*)&Bb[n0 + wn * 64 + dbase];
            b4 *= bscale;
#pragma unroll
            for (int mt = 0; mt < 4; ++mt) {
                int m = m0 + wm * 64 + mt * 16 + l16;
                int bidx = m >> 11, s = m & (SEQ - 1);
                u16x4 pk;
#pragma unroll
                for (int r = 0; r < 4; ++r) pk[r] = f2bf(acc[mt][nt][r] + b4[r]);
                *(u16x4*)&out_bf[outz +
                    ((((size_t)bidx * HEADS + hidx) * SEQ + s) * HDIM + dbase)] = pk;
            }
        }
    } else {
        const size_t outz = (size_t)2 * ((size_t)MTOT * HID);
        const int hidx = (n0 + wn * 64) >> 6;
#pragma unroll
        for (int nt = 0; nt < 4; ++nt) {
            int d = nt * 16 + l16;
            float bias = Bb[n0 + wn * 64 + d];
#pragma unroll
            for (int mt = 0; mt < 4; ++mt) {
                int mbase = m0 + wm * 64 + mt * 16 + grp * 4;
                int bidx = mbase >> 11, sbase = mbase & (SEQ - 1);
                u16x4 pk;
#pragma unroll
                for (int r = 0; r < 4; ++r) pk[r] = f2bf(acc[mt][nt][r] + bias);
                *(u16x4*)&out_bf[outz +
                    ((((size_t)bidx * HEADS + hidx) * HDIM + d) * SEQ + sbase)] = pk;
            }
        }
    }
}

// Barrier-free flash attention, single-wave workgroups, TRANSPOSED score tile.
// S^T = mfma(kf, qf): per lane, one q-column (l16) holds 16 kv scores in regs
// -> softmax is in-lane trees + 2 shuffles (vs 32 shuffles in row layout).
// K register-double-buffered (prefetch next block after S^T); V loaded at
// iteration top, consumed ~1000 cyc later under softmax.  O accumulated as
// O^T -> packed 8B epilogue stores.  XCD-pinned id%8 swizzle (R9: FETCH 81->12MB).
__global__ __launch_bounds__(64) void attn_kernel(
    const unsigned short* __restrict__ Qw, const unsigned short* __restrict__ Kw,
    const unsigned short* __restrict__ VTw, unsigned short* __restrict__ X2)
{
    __shared__ __align__(16) unsigned short Ps[2][16][72];  // per-mt slabs

    const int id = blockIdx.x;                 // 0..2047
    const int xcd = id & 7, k = id >> 3;
    const int bh  = (k >> 6) * 8 + xcd;        // fixed id%8 per (b,h)
    const int k2  = k & 63;
    const int qblk = 31 - (k2 >> 1);           // longest first
    const int qhalf = k2 & 1;
    const int b = bh >> 4, h = bh & 15;

    const int lane = threadIdx.x & 63;
    const int l16  = lane & 15, grp = lane >> 4;

    const int nkb = qblk + 1;
    const int q0  = qblk * 64 + qhalf * 32;

    const size_t head = ((size_t)b * HEADS + h) * (size_t)SEQ * HDIM;

    short8 qf[2][2];   // [mt][ks], loaded once (Q pre-scaled by 1/8)
#pragma unroll
    for (int mt = 0; mt < 2; ++mt)
#pragma unroll
        for (int ks = 0; ks < 2; ++ks)
            qf[mt][ks] = *(const short8*)(Qw + head +
                (size_t)(q0 + mt * 16 + l16) * HDIM + ks * 32 + grp * 8);

    floatx4 o[2][4];                            // O^T: [mt][dt], d=dt*16+grp*4+r, q=l16
    float mi[2] = {-1e30f, -1e30f}, li[2] = {0.f, 0.f};
#pragma unroll
    for (int mt = 0; mt < 2; ++mt)
#pragma unroll
        for (int i = 0; i < 4; ++i) o[mt][i] = (floatx4){0.f, 0.f, 0.f, 0.f};

    short8 kb0[4][2], kb1[4][2], vf[4][2];

    auto loadK = [&](short8 (&kf)[4][2], int kb) {
        const unsigned short* kbase = Kw + head + (size_t)kb * 64 * HDIM;
#pragma unroll
        for (int nt = 0; nt < 4; ++nt)
#pragma unroll
            for (int ks = 0; ks < 2; ++ks)
                kf[nt][ks] = *(const short8*)(kbase +
                    (size_t)(nt * 16 + l16) * HDIM + ks * 32 + grp * 8);
    };

    auto process = [&](short8 (&kfc)[4][2], short8 (&kfn)[4][2], int kb) {
        {   // V for THIS block at iteration top: consumed after softmax
            const unsigned short* vbase = VTw + head + (size_t)kb * 64;
#pragma unroll
            for (int nt = 0; nt < 4; ++nt)
#pragma unroll
                for (int ks = 0; ks < 2; ++ks)
                    vf[nt][ks] = *(const short8*)(vbase +
                        (size_t)(nt * 16 + l16) * SEQ + ks * 32 + grp * 8);
        }
        // S^T: D[row=kv: nt*16+grp*4+r][col=q: l16]
        floatx4 sv[2][4];
#pragma unroll
        for (int mt = 0; mt < 2; ++mt)
#pragma unroll
            for (int nt = 0; nt < 4; ++nt) {
                floatx4 zz = (floatx4){0.f, 0.f, 0.f, 0.f};
                zz = mfma16x16x32bf16(kfc[nt][0], qf[mt][0], zz);
                zz = mfma16x16x32bf16(kfc[nt][1], qf[mt][1], zz);
                sv[mt][nt] = zz;
            }
        if (kb + 1 < nkb) loadK(kfn, kb + 1);   // prefetch next K under softmax

#pragma unroll
        for (int mt = 0; mt < 2; ++mt) {
            // in-lane max over 16 scores, then 2 cross-grp shuffles
            float m01 = fmaxf(fmaxf(sv[mt][0][0], sv[mt][0][1]),
                              fmaxf(sv[mt][0][2], sv[mt][0][3]));
            float m23 = fmaxf(fmaxf(sv[mt][1][0], sv[mt][1][1]),
                              fmaxf(sv[mt][1][2], sv[mt][1][3]));
            float m45 = fmaxf(fmaxf(sv[mt][2][0], sv[mt][2][1]),
                              fmaxf(sv[mt][2][2], sv[mt][2][3]));
            float m67 = fmaxf(fmaxf(sv[mt][3][0], sv[mt][3][1]),
                              fmaxf(sv[mt][3][2], sv[mt][3][3]));
            float mx = fmaxf(fmaxf(m01, m23), fmaxf(m45, m67));
            mx = fmaxf(mx, __shfl_xor(mx, 16));
            mx = fmaxf(mx, __shfl_xor(mx, 32));
            float mn = fmaxf(mi[mt], mx);
            float alpha = __expf(mi[mt] - mn);
            mi[mt] = mn;
            float rs = 0.f;
#pragma unroll
            for (int nt = 0; nt < 4; ++nt) {
                floatx4 p;
#pragma unroll
                for (int r = 0; r < 4; ++r) p[r] = __expf(sv[mt][nt][r] - mn);
                sv[mt][nt] = p;
                rs += (p[0] + p[1]) + (p[2] + p[3]);
            }
            rs += __shfl_xor(rs, 16);
            rs += __shfl_xor(rs, 32);
            li[mt] = li[mt] * alpha + rs;

            // P^T -> LDS: lane packs kv = nt*16+grp*4 .. +3 at row q=l16 (b64)
#pragma unroll
            for (int nt = 0; nt < 4; ++nt) {
                u16x4 pk;
#pragma unroll
                for (int r = 0; r < 4; ++r) pk[r] = f2bf(sv[mt][nt][r]);
                *(u16x4*)&Ps[mt][l16][nt * 16 + grp * 4] = pk;
            }
#pragma unroll
            for (int dt = 0; dt < 4; ++dt) o[mt][dt] *= alpha;  // per-lane alpha

            // pf: A-frag row q=l16, kv-contig (b128); wave-private ordering
            short8 pf0 = *(const short8*)&Ps[mt][l16][grp * 8];
            short8 pf1 = *(const short8*)&Ps[mt][l16][32 + grp * 8];
#pragma unroll
            for (int dt = 0; dt < 4; ++dt) {
                o[mt][dt] = mfma16x16x32bf16(vf[dt][0], pf0, o[mt][dt]);
                o[mt][dt] = mfma16x16x32bf16(vf[dt][1], pf1, o[mt][dt]);
            }
        }
    };

    loadK(kb0, 0);
    int kb = 0;
    while (true) {
        process(kb0, kb1, kb);
        if (++kb >= nkb) break;
        process(kb1, kb0, kb);
        if (++kb >= nkb) break;
    }

    // O^T epilogue: row s = q0+mt*16+l16, 4 consecutive d per lane -> 8B stores
#pragma unroll
    for (int mt = 0; mt < 2; ++mt) {
        float inv = 1.0f / li[mt];
        int srow = q0 + mt * 16 + l16;
#pragma unroll
        for (int dt = 0; dt < 4; ++dt) {
            u16x4 pk;
#pragma unroll
            for (int r = 0; r < 4; ++r) pk[r] = f2bf(o[mt][dt][r] * inv);
            *(u16x4*)&X2[((size_t)b * SEQ + srow) * HID +
                         h * HDIM + dt * 16 + grp * 4] = pk;
        }
    }
}

extern "C" void kernel_launch(void* const* d_in, const int* in_sizes, int n_in,
                              void* d_out, int out_size, void* d_ws, size_t ws_size,
                              hipStream_t stream) {
    int iX, iWq, ibq, iWk, ibk, iWv, ibv, iWo, ibo;
    if (in_sizes[0] == MTOT * HID) {
        iX = 0; iWq = 1; ibq = 2; iWk = 3; ibk = 4; iWv = 5; ibv = 6; iWo = 7; ibo = 8;
    } else {
        iWk = 0; iWo = 1; iWq = 2; iWv = 3; ibk = 4; ibo = 5; ibq = 6; ibv = 7; iX = 8;
    }
    const float* X  = (const float*)d_in[iX];
    const float* Wq = (const float*)d_in[iWq];
    const float* bq = (const float*)d_in[ibq];
    const float* Wk = (const float*)d_in[iWk];
    const float* bk = (const float*)d_in[ibk];
    const float* Wv = (const float*)d_in[iWv];
    const float* bv = (const float*)d_in[ibv];
    const float* Wo = (const float*)d_in[iWo];
    const float* bo = (const float*)d_in[ibo];
    float* out = (float*)d_out;

    unsigned short* ws = (unsigned short*)d_ws;
    const size_t T = (size_t)MTOT * HID;
    unsigned short* qw  = ws;                  // Q  [b][h][s][d] (pre-scaled)
    unsigned short* kw  = ws + T;              // K  [b][h][s][d]
    unsigned short* vtw = ws + 2 * T;          // V^T[b][h][d][s]
    unsigned short* x2  = ws + 3 * T;          // attn out [b][s][hid]
    unsigned short* Xb  = ws + 4 * T;
    unsigned short* Wqb = Xb + T;
    unsigned short* Wkb = Wqb + (size_t)HID * HID;
    unsigned short* Wvb = Wkb + (size_t)HID * HID;
    unsigned short* Wob = Wvb + (size_t)HID * HID;

    cvt5<<<dim3(4096, 5), 256, 0, stream>>>(X, Wq, Wk, Wv, Wo, Xb);
    gemm_bt<1><<<dim3(32, 8, 3), 256, 0, stream>>>(
        Xb, Wqb, Wkb, Wvb, bq, bk, bv, qw, nullptr);
    attn_kernel<<<dim3(2048), 64, 0, stream>>>(qw, kw, vtw, x2);
    gemm_bt<0><<<dim3(32, 8, 1), 256, 0, stream>>>(
        x2, Wob, Wob, Wob, bo, bo, bo, nullptr, out);
}

// Round 11
// 212.235 us; speedup vs baseline: 1.2296x; 1.1439x over previous
//
#include <hip/hip_runtime.h>

#define BS 2
#define SEQ 2048
#define HID 1024
#define HEADS 16
#define HDIM 64
#define MTOT (BS * SEQ)  // 4096

typedef __bf16 bf16x8 __attribute__((ext_vector_type(8)));
typedef float floatx4 __attribute__((ext_vector_type(4)));
typedef short short8 __attribute__((ext_vector_type(8)));
typedef unsigned short u16x4 __attribute__((ext_vector_type(4)));
typedef unsigned int u32x2 __attribute__((ext_vector_type(2)));

__device__ __forceinline__ floatx4 mfma16x16x32bf16(short8 a, short8 b, floatx4 c) {
    return __builtin_amdgcn_mfma_f32_16x16x32_bf16(
        __builtin_bit_cast(bf16x8, a), __builtin_bit_cast(bf16x8, b), c, 0, 0, 0);
}

__device__ __forceinline__ unsigned short f2bf(float f) {
    unsigned int u = __builtin_bit_cast(unsigned int, f);
    u += 0x7fffu + ((u >> 16) & 1u);   // RNE
    return (unsigned short)(u >> 16);
}

#define GLOAD_LDS16(gsrc, ldst)                                                   \
    __builtin_amdgcn_global_load_lds(                                             \
        (const __attribute__((address_space(1))) void*)(gsrc),                    \
        (__attribute__((address_space(3))) void*)(ldst), 16, 0, 0)

// fp32 -> bf16 conversion: X (4M) + Wq,Wk,Wv,Wo (1M each).  Wq pre-scaled 1/8.
__global__ __launch_bounds__(256) void cvt5(
    const float* __restrict__ X, const float* __restrict__ Wq,
    const float* __restrict__ Wk, const float* __restrict__ Wv,
    const float* __restrict__ Wo, unsigned short* __restrict__ dst)
{
    const int y = blockIdx.y;
    const float* src = (y == 0) ? X : (y == 1) ? Wq : (y == 2) ? Wk : (y == 3) ? Wv : Wo;
    const size_t base = (y == 0) ? 0 : (size_t)(4u << 20) + (size_t)(y - 1) * (1u << 20);
    const int n4 = (y == 0) ? (1 << 20) : (1 << 18);
    const float scale = (y == 1) ? 0.125f : 1.0f;
    int i = blockIdx.x * 256 + threadIdx.x;
    if (i >= n4) return;
    floatx4 v = *(const floatx4*)(src + (size_t)i * 4);
    v *= scale;
    unsigned int p0 = (unsigned int)f2bf(v[0]) | ((unsigned int)f2bf(v[1]) << 16);
    unsigned int p1 = (unsigned int)f2bf(v[2]) | ((unsigned int)f2bf(v[3]) << 16);
    u32x2 pk = {p0, p1};
    *(u32x2*)(dst + base + (size_t)i * 4) = pk;
}

// C = X @ W^T + bias, m97 structure.
// MODE 0: fp32 [m][n].
// MODE 1: z=0 Q: swapped epilogue -> [b][h][s][d] (natural).
//         z=1 K: FRAGMENT-MAJOR at ws+T   (attention kf = base+lane*8, coalesced).
//         z=2 V: FRAGMENT-MAJOR at ws+2T  (attention vf = base+lane*8).
// Frag layout per (b,h): ((kvb*4+nt)*2+ks)*512 + (grpf*16+l16)*8 + j, where the
// frag element is A[m16 = l16][k = grpf*8+j] of the 16x16x32 A-operand (kv-major
// for K: m16=s%16, k=d%32; d-major for V: m16=d%16, k=s%32).
template <int MODE>
__global__ __launch_bounds__(256) void gemm_bt(
    const unsigned short* __restrict__ X,
    const unsigned short* __restrict__ W0, const unsigned short* __restrict__ W1,
    const unsigned short* __restrict__ W2,
    const float* __restrict__ B0, const float* __restrict__ B1,
    const float* __restrict__ B2,
    unsigned short* __restrict__ out_bf, float* __restrict__ out_f)
{
    __shared__ __align__(16) unsigned short sA[128 * 32];
    __shared__ __align__(16) unsigned short sB[128 * 32];

    const int tid  = threadIdx.x;
    const int z    = blockIdx.z;
    const unsigned short* W  = (z == 0) ? W0 : (z == 1) ? W1 : W2;
    const float*          Bb = (z == 0) ? B0 : (z == 1) ? B1 : B2;
    const float bscale = (MODE == 1 && z == 0) ? 0.125f : 1.0f;
    const int m0   = blockIdx.x * 128;
    const int n0   = blockIdx.y * 128;
    const int lane = tid & 63, w = tid >> 6;
    const int l16  = lane & 15, grp = lane >> 4;
    const int wm   = w & 1, wn = w >> 1;

    floatx4 acc[4][4];
#pragma unroll
    for (int i = 0; i < 4; ++i)
#pragma unroll
        for (int j = 0; j < 4; ++j) acc[i][j] = (floatx4){0.f, 0.f, 0.f, 0.f};

    auto stage = [&](int kb) {
        const int kcol = kb * 32;
#pragma unroll
        for (int i = 0; i < 2; ++i) {
            int g = tid + i * 256;
            int row = g >> 2, c8 = (g & 3) * 8;
            GLOAD_LDS16(X + (size_t)(m0 + row) * HID + kcol + c8, &sA[g * 8]);
            GLOAD_LDS16(W + (size_t)(n0 + row) * HID + kcol + c8, &sB[g * 8]);
        }
    };

    const bool swapT = (MODE == 1) && (z < 2);
    stage(0);
    for (int kb = 0; kb < 32; ++kb) {
        __syncthreads();
        short8 af[4], bfr[4];
#pragma unroll
        for (int t = 0; t < 4; ++t) {
            af[t]  = *(const short8*)&sA[(wm * 64 + t * 16 + l16) * 32 + grp * 8];
            bfr[t] = *(const short8*)&sB[(wn * 64 + t * 16 + l16) * 32 + grp * 8];
        }
        __syncthreads();
        if (kb + 1 < 32) stage(kb + 1);
        if (swapT) {
#pragma unroll
            for (int mt = 0; mt < 4; ++mt)
#pragma unroll
                for (int nt = 0; nt < 4; ++nt)
                    acc[mt][nt] = mfma16x16x32bf16(bfr[nt], af[mt], acc[mt][nt]);
        } else {
#pragma unroll
            for (int mt = 0; mt < 4; ++mt)
#pragma unroll
                for (int nt = 0; nt < 4; ++nt)
                    acc[mt][nt] = mfma16x16x32bf16(af[mt], bfr[nt], acc[mt][nt]);
        }
    }

    if (MODE == 0) {
#pragma unroll
        for (int nt = 0; nt < 4; ++nt) {
            int n = n0 + wn * 64 + nt * 16 + l16;
            float bias = Bb[n];
#pragma unroll
            for (int mt = 0; mt < 4; ++mt)
#pragma unroll
                for (int r = 0; r < 4; ++r) {
                    int m = m0 + wm * 64 + mt * 16 + grp * 4 + r;
                    out_f[(size_t)m * HID + n] = acc[mt][nt][r] + bias;
                }
        }
    } else if (z == 0) {
        // Q swapped: D[row=n(d): grp*4+r][col=m(s): l16] -> [b][h][s][d] packed
        const int hidx = (n0 + wn * 64) >> 6;
#pragma unroll
        for (int nt = 0; nt < 4; ++nt) {
            int dbase = nt * 16 + grp * 4;
            floatx4 b4 = *(const floatx4*)&Bb[n0 + wn * 64 + dbase];
            b4 *= bscale;
#pragma unroll
            for (int mt = 0; mt < 4; ++mt) {
                int m = m0 + wm * 64 + mt * 16 + l16;
                int bidx = m >> 11, s = m & (SEQ - 1);
                u16x4 pk;
#pragma unroll
                for (int r = 0; r < 4; ++r) pk[r] = f2bf(acc[mt][nt][r] + b4[r]);
                *(u16x4*)&out_bf[
                    ((((size_t)bidx * HEADS + hidx) * SEQ + s) * HDIM + dbase)] = pk;
            }
        }
    } else if (z == 1) {
        // K frag-major (swapped acc): element (s = sblk+mt*16+l16, d = nt*16+grp*4+r)
        const size_t outz = (size_t)MTOT * HID;
        const int hidx = (n0 + wn * 64) >> 6;
        const int sblk = m0 + wm * 64;
        const int bidx = sblk >> 11;
        const int kvb  = (sblk & (SEQ - 1)) >> 6;
        const size_t hbase = outz + ((size_t)bidx * HEADS + hidx) * SEQ * HDIM;
        const int grpf = grp >> 1, j0 = (grp & 1) * 4;
#pragma unroll
        for (int nt = 0; nt < 4; ++nt) {
            floatx4 b4 = *(const floatx4*)&Bb[n0 + wn * 64 + nt * 16 + grp * 4];
#pragma unroll
            for (int mt = 0; mt < 4; ++mt) {
                u16x4 pk;
#pragma unroll
                for (int r = 0; r < 4; ++r) pk[r] = f2bf(acc[mt][nt][r] + b4[r]);
                size_t F = hbase + (size_t)((((kvb * 4 + mt) * 2 + (nt >> 1)) * 512)
                         + ((((nt & 1) * 2 + grpf) * 16 + l16) * 8) + j0);
                *(u16x4*)&out_bf[F] = pk;
            }
        }
    } else {
        // V frag-major (normal acc): element (s = sblk+mt*16+grp*4+r, d = nt*16+l16)
        const size_t outz = (size_t)2 * ((size_t)MTOT * HID);
        const int hidx = (n0 + wn * 64) >> 6;
        const int sblk = m0 + wm * 64;
        const int bidx = sblk >> 11;
        const int kvb  = (sblk & (SEQ - 1)) >> 6;
        const size_t hbase = outz + ((size_t)bidx * HEADS + hidx) * SEQ * HDIM;
        const int grpf = grp >> 1, j0 = (grp & 1) * 4;
#pragma unroll
        for (int nt = 0; nt < 4; ++nt) {
            float bias = Bb[n0 + wn * 64 + nt * 16 + l16];
#pragma unroll
            for (int mt = 0; mt < 4; ++mt) {
                u16x4 pk;
#pragma unroll
                for (int r = 0; r < 4; ++r) pk[r] = f2bf(acc[mt][nt][r] + bias);
                size_t F = hbase + (size_t)((((kvb * 4 + nt) * 2 + (mt >> 1)) * 512)
                         + ((((mt & 1) * 2 + grpf) * 16 + l16) * 8) + j0);
                *(u16x4*)&out_bf[F] = pk;
            }
        }
    }
}

// Barrier-free flash attention.  2048 single-wave workgroups, UNIFORM work:
// each wave owns a 16-row q-quarter and processes q-block pair (j, 31-j)
// back-to-back -> exactly 33 kv-iters per wave (no drain skew).
// K/V loads are fragment-major: one b128 per frag, lane*8 -> 1KB coalesced.
// S^T = mfma(kf, qf) keeps softmax in-lane (2 shuffles per reduction).
// XCD-pinned id%8 (R9-verified: FETCH 81->12 MB).
__global__ __launch_bounds__(64) void attn_kernel(
    const unsigned short* __restrict__ Qw, const unsigned short* __restrict__ Kf,
    const unsigned short* __restrict__ Vf, unsigned short* __restrict__ X2)
{
    __shared__ __align__(16) unsigned short Ps[16][72];

    const int id = blockIdx.x;                 // 0..2047
    const int xcd = id & 7, k = id >> 3;       // k 0..255
    const int bh  = (k >> 6) * 8 + xcd;        // (b,h) pinned to one XCD
    const int slot = k & 63;
    const int pairj = slot >> 2;               // 0..15
    const int quarter = slot & 3;              // 0..3
    const int b = bh >> 4, h = bh & 15;

    const int lane = threadIdx.x & 63;
    const int l16  = lane & 15, grp = lane >> 4;

    const size_t head = ((size_t)b * HEADS + h) * (size_t)SEQ * HDIM;
    const unsigned short* Kh = Kf + head;
    const unsigned short* Vh = Vf + head;

    short8 ka[4][2], kbuf[4][2], vf[4][2];

    auto loadK = [&](short8 (&kf)[4][2], int kb) {
#pragma unroll
        for (int nt = 0; nt < 4; ++nt)
#pragma unroll
            for (int ks = 0; ks < 2; ++ks)
                kf[nt][ks] = *(const short8*)(Kh +
                    (size_t)(((kb * 4 + nt) * 2 + ks) * 512) + lane * 8);
    };

#pragma unroll 1
    for (int phase = 0; phase < 2; ++phase) {
        const int qblk = phase ? (31 - pairj) : pairj;
        const int nkb  = qblk + 1;
        const int q0   = qblk * 64 + quarter * 16;

        short8 qf[2];
#pragma unroll
        for (int ks = 0; ks < 2; ++ks)
            qf[ks] = *(const short8*)(Qw + head +
                (size_t)(q0 + l16) * HDIM + ks * 32 + grp * 8);

        floatx4 o[4];
#pragma unroll
        for (int i = 0; i < 4; ++i) o[i] = (floatx4){0.f, 0.f, 0.f, 0.f};
        float mi = -1e30f, li = 0.f;

        auto process = [&](short8 (&kfc)[4][2], short8 (&kfn)[4][2], int kb) {
            {   // V for this block, consumed after softmax (latency covered)
#pragma unroll
                for (int nt = 0; nt < 4; ++nt)
#pragma unroll
                    for (int ks = 0; ks < 2; ++ks)
                        vf[nt][ks] = *(const short8*)(Vh +
                            (size_t)(((kb * 4 + nt) * 2 + ks) * 512) + lane * 8);
            }
            // S^T: D[row=kv: nt*16+grp*4+r][col=q: l16]
            floatx4 sv[4];
#pragma unroll
            for (int nt = 0; nt < 4; ++nt) {
                floatx4 zz = (floatx4){0.f, 0.f, 0.f, 0.f};
                zz = mfma16x16x32bf16(kfc[nt][0], qf[0], zz);
                zz = mfma16x16x32bf16(kfc[nt][1], qf[1], zz);
                sv[nt] = zz;
            }
            if (kb + 1 < nkb) loadK(kfn, kb + 1);   // prefetch under softmax

            float m01 = fmaxf(fmaxf(sv[0][0], sv[0][1]), fmaxf(sv[0][2], sv[0][3]));
            float m23 = fmaxf(fmaxf(sv[1][0], sv[1][1]), fmaxf(sv[1][2], sv[1][3]));
            float m45 = fmaxf(fmaxf(sv[2][0], sv[2][1]), fmaxf(sv[2][2], sv[2][3]));
            float m67 = fmaxf(fmaxf(sv[3][0], sv[3][1]), fmaxf(sv[3][2], sv[3][3]));
            float mx = fmaxf(fmaxf(m01, m23), fmaxf(m45, m67));
            mx = fmaxf(mx, __shfl_xor(mx, 16));
            mx = fmaxf(mx, __shfl_xor(mx, 32));
            float mn = fmaxf(mi, mx);
            float alpha = __expf(mi - mn);
            mi = mn;
            float rs = 0.f;
#pragma unroll
            for (int nt = 0; nt < 4; ++nt) {
                floatx4 p;
#pragma unroll
                for (int r = 0; r < 4; ++r) p[r] = __expf(sv[nt][r] - mn);
                sv[nt] = p;
                rs += (p[0] + p[1]) + (p[2] + p[3]);
            }
            rs += __shfl_xor(rs, 16);
            rs += __shfl_xor(rs, 32);
            li = li * alpha + rs;

            // P^T -> LDS (b64), wave-private
#pragma unroll
            for (int nt = 0; nt < 4; ++nt) {
                u16x4 pk;
#pragma unroll
                for (int r = 0; r < 4; ++r) pk[r] = f2bf(sv[nt][r]);
                *(u16x4*)&Ps[l16][nt * 16 + grp * 4] = pk;
            }
#pragma unroll
            for (int dt = 0; dt < 4; ++dt) o[dt] *= alpha;

            short8 pf0 = *(const short8*)&Ps[l16][grp * 8];
            short8 pf1 = *(const short8*)&Ps[l16][32 + grp * 8];
#pragma unroll
            for (int dt = 0; dt < 4; ++dt) {
                o[dt] = mfma16x16x32bf16(vf[dt][0], pf0, o[dt]);
                o[dt] = mfma16x16x32bf16(vf[dt][1], pf1, o[dt]);
            }
        };

        loadK(ka, 0);
        int kb = 0;
        while (true) {
            process(ka, kbuf, kb);
            if (++kb >= nkb) break;
            process(kbuf, ka, kb);
            if (++kb >= nkb) break;
        }

        // O^T epilogue: s = q0+l16, lane packs 4 consecutive d (8B stores)
        float inv = 1.0f / li;
        int srow = q0 + l16;
#pragma unroll
        for (int dt = 0; dt < 4; ++dt) {
            u16x4 pk;
#pragma unroll
            for (int r = 0; r < 4; ++r) pk[r] = f2bf(o[dt][r] * inv);
            *(u16x4*)&X2[((size_t)b * SEQ + srow) * HID +
                         h * HDIM + dt * 16 + grp * 4] = pk;
        }
    }
}

extern "C" void kernel_launch(void* const* d_in, const int* in_sizes, int n_in,
                              void* d_out, int out_size, void* d_ws, size_t ws_size,
                              hipStream_t stream) {
    int iX, iWq, ibq, iWk, ibk, iWv, ibv, iWo, ibo;
    if (in_sizes[0] == MTOT * HID) {
        iX = 0; iWq = 1; ibq = 2; iWk = 3; ibk = 4; iWv = 5; ibv = 6; iWo = 7; ibo = 8;
    } else {
        iWk = 0; iWo = 1; iWq = 2; iWv = 3; ibk = 4; ibo = 5; ibq = 6; ibv = 7; iX = 8;
    }
    const float* X  = (const float*)d_in[iX];
    const float* Wq = (const float*)d_in[iWq];
    const float* bq = (const float*)d_in[ibq];
    const float* Wk = (const float*)d_in[iWk];
    const float* bk = (const float*)d_in[ibk];
    const float* Wv = (const float*)d_in[iWv];
    const float* bv = (const float*)d_in[ibv];
    const float* Wo = (const float*)d_in[iWo];
    const float* bo = (const float*)d_in[ibo];
    float* out = (float*)d_out;

    unsigned short* ws = (unsigned short*)d_ws;
    const size_t T = (size_t)MTOT * HID;
    unsigned short* qw  = ws;                  // Q  [b][h][s][d] (pre-scaled)
    unsigned short* kfr = ws + T;              // K  fragment-major per (b,h)
    unsigned short* vfr = ws + 2 * T;          // V  fragment-major per (b,h)
    unsigned short* x2  = ws + 3 * T;          // attn out [b][s][hid]
    unsigned short* Xb  = ws + 4 * T;
    unsigned short* Wqb = Xb + T;
    unsigned short* Wkb = Wqb + (size_t)HID * HID;
    unsigned short* Wvb = Wkb + (size_t)HID * HID;
    unsigned short* Wob = Wvb + (size_t)HID * HID;

    cvt5<<<dim3(4096, 5), 256, 0, stream>>>(X, Wq, Wk, Wv, Wo, Xb);
    gemm_bt<1><<<dim3(32, 8, 3), 256, 0, stream>>>(
        Xb, Wqb, Wkb, Wvb, bq, bk, bv, qw, nullptr);
    attn_kernel<<<dim3(2048), 64, 0, stream>>>(qw, kfr, vfr, x2);
    gemm_bt<0><<<dim3(32, 8, 1), 256, 0, stream>>>(
        x2, Wob, Wob, Wob, bo, bo, bo, nullptr, out);
}

// Round 12
// 195.369 us; speedup vs baseline: 1.3358x; 1.0863x over previous
//
#include <hip/hip_runtime.h>

#define BS 2
#define SEQ 2048
#define HID 1024
#define HEADS 16
#define HDIM 64
#define MTOT (BS * SEQ)  // 4096

typedef __bf16 bf16x8 __attribute__((ext_vector_type(8)));
typedef float floatx4 __attribute__((ext_vector_type(4)));
typedef short short8 __attribute__((ext_vector_type(8)));
typedef unsigned short u16x4 __attribute__((ext_vector_type(4)));
typedef unsigned int u32x2 __attribute__((ext_vector_type(2)));

__device__ __forceinline__ floatx4 mfma16x16x32bf16(short8 a, short8 b, floatx4 c) {
    return __builtin_amdgcn_mfma_f32_16x16x32_bf16(
        __builtin_bit_cast(bf16x8, a), __builtin_bit_cast(bf16x8, b), c, 0, 0, 0);
}

__device__ __forceinline__ unsigned short f2bf(float f) {
    unsigned int u = __builtin_bit_cast(unsigned int, f);
    u += 0x7fffu + ((u >> 16) & 1u);   // RNE
    return (unsigned short)(u >> 16);
}

#define GLOAD_LDS16(gsrc, ldst)                                                   \
    __builtin_amdgcn_global_load_lds(                                             \
        (const __attribute__((address_space(1))) void*)(gsrc),                    \
        (__attribute__((address_space(3))) void*)(ldst), 16, 0, 0)

// fp32 -> bf16 conversion: X (4M) + Wq,Wk,Wv,Wo (1M each).  Wq pre-scaled 1/8.
__global__ __launch_bounds__(256) void cvt5(
    const float* __restrict__ X, const float* __restrict__ Wq,
    const float* __restrict__ Wk, const float* __restrict__ Wv,
    const float* __restrict__ Wo, unsigned short* __restrict__ dst)
{
    const int y = blockIdx.y;
    const float* src = (y == 0) ? X : (y == 1) ? Wq : (y == 2) ? Wk : (y == 3) ? Wv : Wo;
    const size_t base = (y == 0) ? 0 : (size_t)(4u << 20) + (size_t)(y - 1) * (1u << 20);
    const int n4 = (y == 0) ? (1 << 20) : (1 << 18);
    const float scale = (y == 1) ? 0.125f : 1.0f;
    int i = blockIdx.x * 256 + threadIdx.x;
    if (i >= n4) return;
    floatx4 v = *(const floatx4*)(src + (size_t)i * 4);
    v *= scale;
    unsigned int p0 = (unsigned int)f2bf(v[0]) | ((unsigned int)f2bf(v[1]) << 16);
    unsigned int p1 = (unsigned int)f2bf(v[2]) | ((unsigned int)f2bf(v[3]) << 16);
    u32x2 pk = {p0, p1};
    *(u32x2*)(dst + base + (size_t)i * 4) = pk;
}

// C = X @ W^T + bias, BM x BN tile (4 waves 2x2: wave tile BM/2 x BN/2), BK=32.
// Small tiles = many workgroups = latency hiding (R11: 1-3 wg/CU was the GEMM wall).
// MODE 0: fp32 [m][n].
// MODE 1 (BM=64, BN=128): z=0 Q -> [b][h][s][d]; z=1 K frag-major; z=2 V frag-major
// (frag layout consumed by attn: slot ((kvb*4+q16)*2+ks)*512 + lane*8 + j).
template <int BM, int BN, int MODE>
__global__ __launch_bounds__(256) void gemm_bt(
    const unsigned short* __restrict__ X,
    const unsigned short* __restrict__ W0, const unsigned short* __restrict__ W1,
    const unsigned short* __restrict__ W2,
    const float* __restrict__ B0, const float* __restrict__ B1,
    const float* __restrict__ B2,
    unsigned short* __restrict__ out_bf, float* __restrict__ out_f)
{
    constexpr int MT = BM / 32, NT = BN / 32;          // frags per wave
    constexpr int NCH = (BM + BN) * 4;                 // 16B chunks per K-slab
    __shared__ __align__(16) unsigned short sA[BM * 32];
    __shared__ __align__(16) unsigned short sB[BN * 32];

    const int tid  = threadIdx.x;
    const int z    = (MODE == 1) ? blockIdx.z : 0;
    const unsigned short* W  = (z == 0) ? W0 : (z == 1) ? W1 : W2;
    const float*          Bb = (z == 0) ? B0 : (z == 1) ? B1 : B2;
    const float bscale = (MODE == 1 && z == 0) ? 0.125f : 1.0f;
    const int m0   = blockIdx.x * BM;
    const int n0   = blockIdx.y * BN;
    const int lane = tid & 63, w = tid >> 6;
    const int l16  = lane & 15, grp = lane >> 4;
    const int wm   = w & 1, wn = w >> 1;

    floatx4 acc[MT][NT];
#pragma unroll
    for (int i = 0; i < MT; ++i)
#pragma unroll
        for (int j = 0; j < NT; ++j) acc[i][j] = (floatx4){0.f, 0.f, 0.f, 0.f};

    auto stage = [&](int kb) {
        const int kcol = kb * 32;
#pragma unroll
        for (int i = 0; i < NCH / 256; ++i) {
            int g = tid + i * 256;
            if (g < BM * 4) {
                int row = g >> 2, c8 = (g & 3) * 8;
                GLOAD_LDS16(X + (size_t)(m0 + row) * HID + kcol + c8, &sA[g * 8]);
            } else {
                int g2 = g - BM * 4;
                int row = g2 >> 2, c8 = (g2 & 3) * 8;
                GLOAD_LDS16(W + (size_t)(n0 + row) * HID + kcol + c8, &sB[g2 * 8]);
            }
        }
    };

    const bool swapT = (MODE == 1) && (z < 2);
    stage(0);
    for (int kb = 0; kb < 32; ++kb) {
        __syncthreads();
        short8 af[MT], bfr[NT];
#pragma unroll
        for (int t = 0; t < MT; ++t)
            af[t] = *(const short8*)&sA[(wm * (BM / 2) + t * 16 + l16) * 32 + grp * 8];
#pragma unroll
        for (int t = 0; t < NT; ++t)
            bfr[t] = *(const short8*)&sB[(wn * (BN / 2) + t * 16 + l16) * 32 + grp * 8];
        __syncthreads();
        if (kb + 1 < 32) stage(kb + 1);
        if (swapT) {
#pragma unroll
            for (int mt = 0; mt < MT; ++mt)
#pragma unroll
                for (int nt = 0; nt < NT; ++nt)
                    acc[mt][nt] = mfma16x16x32bf16(bfr[nt], af[mt], acc[mt][nt]);
        } else {
#pragma unroll
            for (int mt = 0; mt < MT; ++mt)
#pragma unroll
                for (int nt = 0; nt < NT; ++nt)
                    acc[mt][nt] = mfma16x16x32bf16(af[mt], bfr[nt], acc[mt][nt]);
        }
    }

    if (MODE == 0) {
        // D[row=m: grp*4+r][col=n: l16] -> fp32 [m][n]
#pragma unroll
        for (int nt = 0; nt < NT; ++nt) {
            int n = n0 + wn * (BN / 2) + nt * 16 + l16;
            float bias = Bb[n];
#pragma unroll
            for (int mt = 0; mt < MT; ++mt)
#pragma unroll
                for (int r = 0; r < 4; ++r) {
                    int m = m0 + wm * (BM / 2) + mt * 16 + grp * 4 + r;
                    out_f[(size_t)m * HID + n] = acc[mt][nt][r] + bias;
                }
        }
    } else if (z == 0) {
        // Q swapped: D[row=n(d): grp*4+r][col=m(s): l16] -> [b][h][s][d] packed
        const int hidx = (n0 + wn * 64) >> 6;
#pragma unroll
        for (int nt = 0; nt < NT; ++nt) {
            int dbase = nt * 16 + grp * 4;
            floatx4 b4 = *(const floatx4*)&Bb[n0 + wn * 64 + dbase];
            b4 *= bscale;
#pragma unroll
            for (int mt = 0; mt < MT; ++mt) {
                int m = m0 + wm * 32 + mt * 16 + l16;
                int bidx = m >> 11, s = m & (SEQ - 1);
                u16x4 pk;
#pragma unroll
                for (int r = 0; r < 4; ++r) pk[r] = f2bf(acc[mt][nt][r] + b4[r]);
                *(u16x4*)&out_bf[
                    ((((size_t)bidx * HEADS + hidx) * SEQ + s) * HDIM + dbase)] = pk;
            }
        }
    } else if (z == 1) {
        // K frag-major (swapped): elem (s = m0+wm*32+mt*16+l16, d = nt*16+grp*4+r)
        const size_t outz = (size_t)MTOT * HID;
        const int hidx = (n0 + wn * 64) >> 6;
        const int bidx = m0 >> 11;
        const int kvb  = (m0 & (SEQ - 1)) >> 6;
        const size_t hbase = outz + ((size_t)bidx * HEADS + hidx) * SEQ * HDIM;
        const int grpf = grp >> 1, j0 = (grp & 1) * 4;
#pragma unroll
        for (int nt = 0; nt < NT; ++nt) {
            floatx4 b4 = *(const floatx4*)&Bb[n0 + wn * 64 + nt * 16 + grp * 4];
#pragma unroll
            for (int mt = 0; mt < MT; ++mt) {
                u16x4 pk;
#pragma unroll
                for (int r = 0; r < 4; ++r) pk[r] = f2bf(acc[mt][nt][r] + b4[r]);
                size_t F = hbase
                    + (size_t)((((kvb * 4 + (wm * 2 + mt)) * 2 + (nt >> 1)) * 512)
                    + ((((nt & 1) * 2 + grpf) * 16 + l16) * 8) + j0);
                *(u16x4*)&out_bf[F] = pk;
            }
        }
    } else {
        // V frag-major (normal): elem (s = m0+wm*32+mt*16+grp*4+r, d = nt*16+l16)
        const size_t outz = (size_t)2 * ((size_t)MTOT * HID);
        const int hidx = (n0 + wn * 64) >> 6;
        const int bidx = m0 >> 11;
        const int kvb  = (m0 & (SEQ - 1)) >> 6;
        const size_t hbase = outz + ((size_t)bidx * HEADS + hidx) * SEQ * HDIM;
        const int j0 = (grp & 1) * 4;
#pragma unroll
        for (int nt = 0; nt < NT; ++nt) {
            float bias = Bb[n0 + wn * 64 + nt * 16 + l16];
#pragma unroll
            for (int mt = 0; mt < MT; ++mt) {
                u16x4 pk;
#pragma unroll
                for (int r = 0; r < 4; ++r) pk[r] = f2bf(acc[mt][nt][r] + bias);
                size_t F = hbase + (size_t)((((kvb * 4 + nt) * 2 + wm) * 512)
                    + (((mt * 2 + (grp >> 1)) * 16 + l16) * 8) + j0);
                *(u16x4*)&out_bf[F] = pk;
            }
        }
    }
}

// Barrier-free flash attention (R10-verified).  2048 single-wave workgroups,
// uniform 33 kv-iters (q-block pair j/31-j), frag-major coalesced K/V loads,
// in-lane transposed softmax, XCD-pinned id%8.
__global__ __launch_bounds__(64) void attn_kernel(
    const unsigned short* __restrict__ Qw, const unsigned short* __restrict__ Kf,
    const unsigned short* __restrict__ Vf, unsigned short* __restrict__ X2)
{
    __shared__ __align__(16) unsigned short Ps[16][72];

    const int id = blockIdx.x;                 // 0..2047
    const int xcd = id & 7, k = id >> 3;
    const int bh  = (k >> 6) * 8 + xcd;
    const int slot = k & 63;
    const int pairj = slot >> 2;
    const int quarter = slot & 3;
    const int b = bh >> 4, h = bh & 15;

    const int lane = threadIdx.x & 63;
    const int l16  = lane & 15, grp = lane >> 4;

    const size_t head = ((size_t)b * HEADS + h) * (size_t)SEQ * HDIM;
    const unsigned short* Kh = Kf + head;
    const unsigned short* Vh = Vf + head;

    short8 ka[4][2], kbuf[4][2], vf[4][2];

    auto loadK = [&](short8 (&kf)[4][2], int kb) {
#pragma unroll
        for (int nt = 0; nt < 4; ++nt)
#pragma unroll
            for (int ks = 0; ks < 2; ++ks)
                kf[nt][ks] = *(const short8*)(Kh +
                    (size_t)(((kb * 4 + nt) * 2 + ks) * 512) + lane * 8);
    };

#pragma unroll 1
    for (int phase = 0; phase < 2; ++phase) {
        const int qblk = phase ? (31 - pairj) : pairj;
        const int nkb  = qblk + 1;
        const int q0   = qblk * 64 + quarter * 16;

        short8 qf[2];
#pragma unroll
        for (int ks = 0; ks < 2; ++ks)
            qf[ks] = *(const short8*)(Qw + head +
                (size_t)(q0 + l16) * HDIM + ks * 32 + grp * 8);

        floatx4 o[4];
#pragma unroll
        for (int i = 0; i < 4; ++i) o[i] = (floatx4){0.f, 0.f, 0.f, 0.f};
        float mi = -1e30f, li = 0.f;

        auto process = [&](short8 (&kfc)[4][2], short8 (&kfn)[4][2], int kb) {
            {
#pragma unroll
                for (int nt = 0; nt < 4; ++nt)
#pragma unroll
                    for (int ks = 0; ks < 2; ++ks)
                        vf[nt][ks] = *(const short8*)(Vh +
                            (size_t)(((kb * 4 + nt) * 2 + ks) * 512) + lane * 8);
            }
            floatx4 sv[4];
#pragma unroll
            for (int nt = 0; nt < 4; ++nt) {
                floatx4 zz = (floatx4){0.f, 0.f, 0.f, 0.f};
                zz = mfma16x16x32bf16(kfc[nt][0], qf[0], zz);
                zz = mfma16x16x32bf16(kfc[nt][1], qf[1], zz);
                sv[nt] = zz;
            }
            if (kb + 1 < nkb) loadK(kfn, kb + 1);

            float m01 = fmaxf(fmaxf(sv[0][0], sv[0][1]), fmaxf(sv[0][2], sv[0][3]));
            float m23 = fmaxf(fmaxf(sv[1][0], sv[1][1]), fmaxf(sv[1][2], sv[1][3]));
            float m45 = fmaxf(fmaxf(sv[2][0], sv[2][1]), fmaxf(sv[2][2], sv[2][3]));
            float m67 = fmaxf(fmaxf(sv[3][0], sv[3][1]), fmaxf(sv[3][2], sv[3][3]));
            float mx = fmaxf(fmaxf(m01, m23), fmaxf(m45, m67));
            mx = fmaxf(mx, __shfl_xor(mx, 16));
            mx = fmaxf(mx, __shfl_xor(mx, 32));
            float mn = fmaxf(mi, mx);
            float alpha = __expf(mi - mn);
            mi = mn;
            float rs = 0.f;
#pragma unroll
            for (int nt = 0; nt < 4; ++nt) {
                floatx4 p;
#pragma unroll
                for (int r = 0; r < 4; ++r) p[r] = __expf(sv[nt][r] - mn);
                sv[nt] = p;
                rs += (p[0] + p[1]) + (p[2] + p[3]);
            }
            rs += __shfl_xor(rs, 16);
            rs += __shfl_xor(rs, 32);
            li = li * alpha + rs;

#pragma unroll
            for (int nt = 0; nt < 4; ++nt) {
                u16x4 pk;
#pragma unroll
                for (int r = 0; r < 4; ++r) pk[r] = f2bf(sv[nt][r]);
                *(u16x4*)&Ps[l16][nt * 16 + grp * 4] = pk;
            }
#pragma unroll
            for (int dt = 0; dt < 4; ++dt) o[dt] *= alpha;

            short8 pf0 = *(const short8*)&Ps[l16][grp * 8];
            short8 pf1 = *(const short8*)&Ps[l16][32 + grp * 8];
#pragma unroll
            for (int dt = 0; dt < 4; ++dt) {
                o[dt] = mfma16x16x32bf16(vf[dt][0], pf0, o[dt]);
                o[dt] = mfma16x16x32bf16(vf[dt][1], pf1, o[dt]);
            }
        };

        loadK(ka, 0);
        int kb = 0;
        while (true) {
            process(ka, kbuf, kb);
            if (++kb >= nkb) break;
            process(kbuf, ka, kb);
            if (++kb >= nkb) break;
        }

        float inv = 1.0f / li;
        int srow = q0 + l16;
#pragma unroll
        for (int dt = 0; dt < 4; ++dt) {
            u16x4 pk;
#pragma unroll
            for (int r = 0; r < 4; ++r) pk[r] = f2bf(o[dt][r] * inv);
            *(u16x4*)&X2[((size_t)b * SEQ + srow) * HID +
                         h * HDIM + dt * 16 + grp * 4] = pk;
        }
    }
}

extern "C" void kernel_launch(void* const* d_in, const int* in_sizes, int n_in,
                              void* d_out, int out_size, void* d_ws, size_t ws_size,
                              hipStream_t stream) {
    int iX, iWq, ibq, iWk, ibk, iWv, ibv, iWo, ibo;
    if (in_sizes[0] == MTOT * HID) {
        iX = 0; iWq = 1; ibq = 2; iWk = 3; ibk = 4; iWv = 5; ibv = 6; iWo = 7; ibo = 8;
    } else {
        iWk = 0; iWo = 1; iWq = 2; iWv = 3; ibk = 4; ibo = 5; ibq = 6; ibv = 7; iX = 8;
    }
    const float* X  = (const float*)d_in[iX];
    const float* Wq = (const float*)d_in[iWq];
    const float* bq = (const float*)d_in[ibq];
    const float* Wk = (const float*)d_in[iWk];
    const float* bk = (const float*)d_in[ibk];
    const float* Wv = (const float*)d_in[iWv];
    const float* bv = (const float*)d_in[ibv];
    const float* Wo = (const float*)d_in[iWo];
    const float* bo = (const float*)d_in[ibo];
    float* out = (float*)d_out;

    unsigned short* ws = (unsigned short*)d_ws;
    const size_t T = (size_t)MTOT * HID;
    unsigned short* qw  = ws;                  // Q  [b][h][s][d] (pre-scaled)
    unsigned short* kfr = ws + T;              // K  fragment-major per (b,h)
    unsigned short* vfr = ws + 2 * T;          // V  fragment-major per (b,h)
    unsigned short* x2  = ws + 3 * T;          // attn out [b][s][hid]
    unsigned short* Xb  = ws + 4 * T;
    unsigned short* Wqb = Xb + T;
    unsigned short* Wkb = Wqb + (size_t)HID * HID;
    unsigned short* Wvb = Wkb + (size_t)HID * HID;
    unsigned short* Wob = Wvb + (size_t)HID * HID;

    cvt5<<<dim3(4096, 5), 256, 0, stream>>>(X, Wq, Wk, Wv, Wo, Xb);
    // QKV: 64x128 tiles -> 1536 wg (6/CU) for latency hiding
    gemm_bt<64, 128, 1><<<dim3(64, 8, 3), 256, 0, stream>>>(
        Xb, Wqb, Wkb, Wvb, bq, bk, bv, qw, nullptr);
    attn_kernel<<<dim3(2048), 64, 0, stream>>>(qw, kfr, vfr, x2);
    // out-proj: 64x64 tiles -> 1024 wg (4/CU)
    gemm_bt<64, 64, 0><<<dim3(64, 16, 1), 256, 0, stream>>>(
        x2, Wob, Wob, Wob, bo, bo, bo, nullptr, out);
}

// Round 13
// 192.759 us; speedup vs baseline: 1.3538x; 1.0135x over previous
//
#include <hip/hip_runtime.h>

#define BS 2
#define SEQ 2048
#define HID 1024
#define HEADS 16
#define HDIM 64
#define MTOT (BS * SEQ)  // 4096

typedef __bf16 bf16x8 __attribute__((ext_vector_type(8)));
typedef float floatx4 __attribute__((ext_vector_type(4)));
typedef short short8 __attribute__((ext_vector_type(8)));
typedef unsigned short u16x4 __attribute__((ext_vector_type(4)));
typedef unsigned int u32x2 __attribute__((ext_vector_type(2)));

__device__ __forceinline__ floatx4 mfma16x16x32bf16(short8 a, short8 b, floatx4 c) {
    return __builtin_amdgcn_mfma_f32_16x16x32_bf16(
        __builtin_bit_cast(bf16x8, a), __builtin_bit_cast(bf16x8, b), c, 0, 0, 0);
}

__device__ __forceinline__ unsigned short f2bf(float f) {
    unsigned int u = __builtin_bit_cast(unsigned int, f);
    u += 0x7fffu + ((u >> 16) & 1u);   // RNE
    return (unsigned short)(u >> 16);
}

#define GLOAD_LDS16(gsrc, ldst)                                                   \
    __builtin_amdgcn_global_load_lds(                                             \
        (const __attribute__((address_space(1))) void*)(gsrc),                    \
        (__attribute__((address_space(3))) void*)(ldst), 16, 0, 0)

// fp32 -> bf16 conversion: X (4M) + Wq,Wk,Wv,Wo (1M each).  Wq pre-scaled 1/8.
__global__ __launch_bounds__(256) void cvt5(
    const float* __restrict__ X, const float* __restrict__ Wq,
    const float* __restrict__ Wk, const float* __restrict__ Wv,
    const float* __restrict__ Wo, unsigned short* __restrict__ dst)
{
    const int y = blockIdx.y;
    const float* src = (y == 0) ? X : (y == 1) ? Wq : (y == 2) ? Wk : (y == 3) ? Wv : Wo;
    const size_t base = (y == 0) ? 0 : (size_t)(4u << 20) + (size_t)(y - 1) * (1u << 20);
    const int n4 = (y == 0) ? (1 << 20) : (1 << 18);
    const float scale = (y == 1) ? 0.125f : 1.0f;
    int i = blockIdx.x * 256 + threadIdx.x;
    if (i >= n4) return;
    floatx4 v = *(const floatx4*)(src + (size_t)i * 4);
    v *= scale;
    unsigned int p0 = (unsigned int)f2bf(v[0]) | ((unsigned int)f2bf(v[1]) << 16);
    unsigned int p1 = (unsigned int)f2bf(v[2]) | ((unsigned int)f2bf(v[3]) << 16);
    u32x2 pk = {p0, p1};
    *(u32x2*)(dst + base + (size_t)i * 4) = pk;
}

// FUSED QKV: one workgroup stages the X-slab ONCE + 3 W-slabs, 24 MFMA per
// barrier-pair (3x density of the split-z version -> amortizes the vmcnt(0)
// barrier drain).  BM=64, BN=128, grid (64,8)=512 wg.
// Q,K: swapped-operand MFMA (D=n x m); V: normal.  Epilogues = R12-verified:
//   Q -> [b][h][s][d] packed;  K,V -> fragment-major for the attention reader.
__global__ __launch_bounds__(256) void gemm_qkv(
    const unsigned short* __restrict__ X,
    const unsigned short* __restrict__ W0, const unsigned short* __restrict__ W1,
    const unsigned short* __restrict__ W2,
    const float* __restrict__ B0, const float* __restrict__ B1,
    const float* __restrict__ B2,
    unsigned short* __restrict__ out_bf)
{
    __shared__ __align__(16) unsigned short sA[64 * 32];
    __shared__ __align__(16) unsigned short sB[3][128 * 32];

    const int tid  = threadIdx.x;
    const int m0   = blockIdx.x * 64;
    const int n0   = blockIdx.y * 128;
    const int lane = tid & 63, w = tid >> 6;
    const int l16  = lane & 15, grp = lane >> 4;
    const int wm   = w & 1, wn = w >> 1;

    const unsigned short* Wz[3] = {W0, W1, W2};

    floatx4 acc[3][2][4];
#pragma unroll
    for (int z = 0; z < 3; ++z)
#pragma unroll
        for (int i = 0; i < 2; ++i)
#pragma unroll
            for (int j = 0; j < 4; ++j) acc[z][i][j] = (floatx4){0.f, 0.f, 0.f, 0.f};

    auto stage = [&](int kb) {
        const int kcol = kb * 32;
        {   // A: 256 chunks (64 rows x 4)
            int row = tid >> 2, c8 = (tid & 3) * 8;
            GLOAD_LDS16(X + (size_t)(m0 + row) * HID + kcol + c8, &sA[tid * 8]);
        }
#pragma unroll
        for (int i = 0; i < 6; ++i) {      // W: 3 x 512 chunks; z compile-time per i
            int g2 = tid + i * 256;
            int z = g2 >> 9, g3 = g2 & 511;
            int row = g3 >> 2, c8 = (g3 & 3) * 8;
            GLOAD_LDS16(Wz[z] + (size_t)(n0 + row) * HID + kcol + c8, &sB[z][g3 * 8]);
        }
    };

    stage(0);
    for (int kb = 0; kb < 32; ++kb) {
        __syncthreads();
        short8 af[2], bfr[3][4];
#pragma unroll
        for (int t = 0; t < 2; ++t)
            af[t] = *(const short8*)&sA[(wm * 32 + t * 16 + l16) * 32 + grp * 8];
#pragma unroll
        for (int z = 0; z < 3; ++z)
#pragma unroll
            for (int t = 0; t < 4; ++t)
                bfr[z][t] = *(const short8*)&sB[z][(wn * 64 + t * 16 + l16) * 32 + grp * 8];
        __syncthreads();
        if (kb + 1 < 32) stage(kb + 1);
#pragma unroll
        for (int mt = 0; mt < 2; ++mt)
#pragma unroll
            for (int nt = 0; nt < 4; ++nt) {
                acc[0][mt][nt] = mfma16x16x32bf16(bfr[0][nt], af[mt], acc[0][mt][nt]);
                acc[1][mt][nt] = mfma16x16x32bf16(bfr[1][nt], af[mt], acc[1][mt][nt]);
                acc[2][mt][nt] = mfma16x16x32bf16(af[mt], bfr[2][nt], acc[2][mt][nt]);
            }
    }

    const int hidx = (n0 + wn * 64) >> 6;
    {   // Q (swapped): D[row=n(d): grp*4+r][col=m(s): l16] -> [b][h][s][d]
#pragma unroll
        for (int nt = 0; nt < 4; ++nt) {
            int dbase = nt * 16 + grp * 4;
            floatx4 b4 = *(const floatx4*)&B0[n0 + wn * 64 + dbase];
            b4 *= 0.125f;                         // matches pre-scaled Wq
#pragma unroll
            for (int mt = 0; mt < 2; ++mt) {
                int m = m0 + wm * 32 + mt * 16 + l16;
                int bidx = m >> 11, s = m & (SEQ - 1);
                u16x4 pk;
#pragma unroll
                for (int r = 0; r < 4; ++r) pk[r] = f2bf(acc[0][mt][nt][r] + b4[r]);
                *(u16x4*)&out_bf[
                    ((((size_t)bidx * HEADS + hidx) * SEQ + s) * HDIM + dbase)] = pk;
            }
        }
    }
    {   // K frag-major (swapped): elem (s = m0+wm*32+mt*16+l16, d = nt*16+grp*4+r)
        const size_t outz = (size_t)MTOT * HID;
        const int bidx = m0 >> 11;
        const int kvb  = (m0 & (SEQ - 1)) >> 6;
        const size_t hbase = outz + ((size_t)bidx * HEADS + hidx) * SEQ * HDIM;
        const int grpf = grp >> 1, j0 = (grp & 1) * 4;
#pragma unroll
        for (int nt = 0; nt < 4; ++nt) {
            floatx4 b4 = *(const floatx4*)&B1[n0 + wn * 64 + nt * 16 + grp * 4];
#pragma unroll
            for (int mt = 0; mt < 2; ++mt) {
                u16x4 pk;
#pragma unroll
                for (int r = 0; r < 4; ++r) pk[r] = f2bf(acc[1][mt][nt][r] + b4[r]);
                size_t F = hbase
                    + (size_t)((((kvb * 4 + (wm * 2 + mt)) * 2 + (nt >> 1)) * 512)
                    + ((((nt & 1) * 2 + grpf) * 16 + l16) * 8) + j0);
                *(u16x4*)&out_bf[F] = pk;
            }
        }
    }
    {   // V frag-major (normal): elem (s = m0+wm*32+mt*16+grp*4+r, d = nt*16+l16)
        const size_t outz = (size_t)2 * ((size_t)MTOT * HID);
        const int bidx = m0 >> 11;
        const int kvb  = (m0 & (SEQ - 1)) >> 6;
        const size_t hbase = outz + ((size_t)bidx * HEADS + hidx) * SEQ * HDIM;
        const int j0 = (grp & 1) * 4;
#pragma unroll
        for (int nt = 0; nt < 4; ++nt) {
            float bias = B2[n0 + wn * 64 + nt * 16 + l16];
#pragma unroll
            for (int mt = 0; mt < 2; ++mt) {
                u16x4 pk;
#pragma unroll
                for (int r = 0; r < 4; ++r) pk[r] = f2bf(acc[2][mt][nt][r] + bias);
                size_t F = hbase + (size_t)((((kvb * 4 + nt) * 2 + wm) * 512)
                    + (((mt * 2 + (grp >> 1)) * 16 + l16) * 8) + j0);
                *(u16x4*)&out_bf[F] = pk;
            }
        }
    }
}

// Out-projection: BM x BN tile, fp32 output [m][n].  64x128 -> 512 wg, 8 MFMA
// per barrier-pair (R12: 64x64's 4 MFMA/iter wasted half the barrier amortization).
template <int BM, int BN>
__global__ __launch_bounds__(256) void gemm_out(
    const unsigned short* __restrict__ X, const unsigned short* __restrict__ W,
    const float* __restrict__ Bb, float* __restrict__ out_f)
{
    constexpr int MT = BM / 32, NT = BN / 32;
    constexpr int NCH = (BM + BN) * 4;
    __shared__ __align__(16) unsigned short sA[BM * 32];
    __shared__ __align__(16) unsigned short sB[BN * 32];

    const int tid  = threadIdx.x;
    const int m0   = blockIdx.x * BM;
    const int n0   = blockIdx.y * BN;
    const int lane = tid & 63, w = tid >> 6;
    const int l16  = lane & 15, grp = lane >> 4;
    const int wm   = w & 1, wn = w >> 1;

    floatx4 acc[MT][NT];
#pragma unroll
    for (int i = 0; i < MT; ++i)
#pragma unroll
        for (int j = 0; j < NT; ++j) acc[i][j] = (floatx4){0.f, 0.f, 0.f, 0.f};

    auto stage = [&](int kb) {
        const int kcol = kb * 32;
#pragma unroll
        for (int i = 0; i < NCH / 256; ++i) {
            int g = tid + i * 256;
            if (g < BM * 4) {
                int row = g >> 2, c8 = (g & 3) * 8;
                GLOAD_LDS16(X + (size_t)(m0 + row) * HID + kcol + c8, &sA[g * 8]);
            } else {
                int g2 = g - BM * 4;
                int row = g2 >> 2, c8 = (g2 & 3) * 8;
                GLOAD_LDS16(W + (size_t)(n0 + row) * HID + kcol + c8, &sB[g2 * 8]);
            }
        }
    };

    stage(0);
    for (int kb = 0; kb < 32; ++kb) {
        __syncthreads();
        short8 af[MT], bfr[NT];
#pragma unroll
        for (int t = 0; t < MT; ++t)
            af[t] = *(const short8*)&sA[(wm * (BM / 2) + t * 16 + l16) * 32 + grp * 8];
#pragma unroll
        for (int t = 0; t < NT; ++t)
            bfr[t] = *(const short8*)&sB[(wn * (BN / 2) + t * 16 + l16) * 32 + grp * 8];
        __syncthreads();
        if (kb + 1 < 32) stage(kb + 1);
#pragma unroll
        for (int mt = 0; mt < MT; ++mt)
#pragma unroll
            for (int nt = 0; nt < NT; ++nt)
                acc[mt][nt] = mfma16x16x32bf16(af[mt], bfr[nt], acc[mt][nt]);
    }

    // D[row=m: grp*4+r][col=n: l16] -> fp32 [m][n]
#pragma unroll
    for (int nt = 0; nt < NT; ++nt) {
        int n = n0 + wn * (BN / 2) + nt * 16 + l16;
        float bias = Bb[n];
#pragma unroll
        for (int mt = 0; mt < MT; ++mt)
#pragma unroll
            for (int r = 0; r < 4; ++r) {
                int m = m0 + wm * (BM / 2) + mt * 16 + grp * 4 + r;
                out_f[(size_t)m * HID + n] = acc[mt][nt][r] + bias;
            }
    }
}

// Barrier-free flash attention (R10-verified).  2048 single-wave workgroups,
// uniform 33 kv-iters (q-block pair j/31-j), frag-major coalesced K/V loads,
// in-lane transposed softmax, XCD-pinned id%8.
__global__ __launch_bounds__(64) void attn_kernel(
    const unsigned short* __restrict__ Qw, const unsigned short* __restrict__ Kf,
    const unsigned short* __restrict__ Vf, unsigned short* __restrict__ X2)
{
    __shared__ __align__(16) unsigned short Ps[16][72];

    const int id = blockIdx.x;                 // 0..2047
    const int xcd = id & 7, k = id >> 3;
    const int bh  = (k >> 6) * 8 + xcd;
    const int slot = k & 63;
    const int pairj = slot >> 2;
    const int quarter = slot & 3;
    const int b = bh >> 4, h = bh & 15;

    const int lane = threadIdx.x & 63;
    const int l16  = lane & 15, grp = lane >> 4;

    const size_t head = ((size_t)b * HEADS + h) * (size_t)SEQ * HDIM;
    const unsigned short* Kh = Kf + head;
    const unsigned short* Vh = Vf + head;

    short8 ka[4][2], kbuf[4][2], vf[4][2];

    auto loadK = [&](short8 (&kf)[4][2], int kb) {
#pragma unroll
        for (int nt = 0; nt < 4; ++nt)
#pragma unroll
            for (int ks = 0; ks < 2; ++ks)
                kf[nt][ks] = *(const short8*)(Kh +
                    (size_t)(((kb * 4 + nt) * 2 + ks) * 512) + lane * 8);
    };

#pragma unroll 1
    for (int phase = 0; phase < 2; ++phase) {
        const int qblk = phase ? (31 - pairj) : pairj;
        const int nkb  = qblk + 1;
        const int q0   = qblk * 64 + quarter * 16;

        short8 qf[2];
#pragma unroll
        for (int ks = 0; ks < 2; ++ks)
            qf[ks] = *(const short8*)(Qw + head +
                (size_t)(q0 + l16) * HDIM + ks * 32 + grp * 8);

        floatx4 o[4];
#pragma unroll
        for (int i = 0; i < 4; ++i) o[i] = (floatx4){0.f, 0.f, 0.f, 0.f};
        float mi = -1e30f, li = 0.f;

        auto process = [&](short8 (&kfc)[4][2], short8 (&kfn)[4][2], int kb) {
            {
#pragma unroll
                for (int nt = 0; nt < 4; ++nt)
#pragma unroll
                    for (int ks = 0; ks < 2; ++ks)
                        vf[nt][ks] = *(const short8*)(Vh +
                            (size_t)(((kb * 4 + nt) * 2 + ks) * 512) + lane * 8);
            }
            floatx4 sv[4];
#pragma unroll
            for (int nt = 0; nt < 4; ++nt) {
                floatx4 zz = (floatx4){0.f, 0.f, 0.f, 0.f};
                zz = mfma16x16x32bf16(kfc[nt][0], qf[0], zz);
                zz = mfma16x16x32bf16(kfc[nt][1], qf[1], zz);
                sv[nt] = zz;
            }
            if (kb + 1 < nkb) loadK(kfn, kb + 1);

            float m01 = fmaxf(fmaxf(sv[0][0], sv[0][1]), fmaxf(sv[0][2], sv[0][3]));
            float m23 = fmaxf(fmaxf(sv[1][0], sv[1][1]), fmaxf(sv[1][2], sv[1][3]));
            float m45 = fmaxf(fmaxf(sv[2][0], sv[2][1]), fmaxf(sv[2][2], sv[2][3]));
            float m67 = fmaxf(fmaxf(sv[3][0], sv[3][1]), fmaxf(sv[3][2], sv[3][3]));
            float mx = fmaxf(fmaxf(m01, m23), fmaxf(m45, m67));
            mx = fmaxf(mx, __shfl_xor(mx, 16));
            mx = fmaxf(mx, __shfl_xor(mx, 32));
            float mn = fmaxf(mi, mx);
            float alpha = __expf(mi - mn);
            mi = mn;
            float rs = 0.f;
#pragma unroll
            for (int nt = 0; nt < 4; ++nt) {
                floatx4 p;
#pragma unroll
                for (int r = 0; r < 4; ++r) p[r] = __expf(sv[nt][r] - mn);
                sv[nt] = p;
                rs += (p[0] + p[1]) + (p[2] + p[3]);
            }
            rs += __shfl_xor(rs, 16);
            rs += __shfl_xor(rs, 32);
            li = li * alpha + rs;

#pragma unroll
            for (int nt = 0; nt < 4; ++nt) {
                u16x4 pk;
#pragma unroll
                for (int r = 0; r < 4; ++r) pk[r] = f2bf(sv[nt][r]);
                *(u16x4*)&Ps[l16][nt * 16 + grp * 4] = pk;
            }
#pragma unroll
            for (int dt = 0; dt < 4; ++dt) o[dt] *= alpha;

            short8 pf0 = *(const short8*)&Ps[l16][grp * 8];
            short8 pf1 = *(const short8*)&Ps[l16][32 + grp * 8];
#pragma unroll
            for (int dt = 0; dt < 4; ++dt) {
                o[dt] = mfma16x16x32bf16(vf[dt][0], pf0, o[dt]);
                o[dt] = mfma16x16x32bf16(vf[dt][1], pf1, o[dt]);
            }
        };

        loadK(ka, 0);
        int kb = 0;
        while (true) {
            process(ka, kbuf, kb);
            if (++kb >= nkb) break;
            process(kbuf, ka, kb);
            if (++kb >= nkb) break;
        }

        float inv = 1.0f / li;
        int srow = q0 + l16;
#pragma unroll
        for (int dt = 0; dt < 4; ++dt) {
            u16x4 pk;
#pragma unroll
            for (int r = 0; r < 4; ++r) pk[r] = f2bf(o[dt][r] * inv);
            *(u16x4*)&X2[((size_t)b * SEQ + srow) * HID +
                         h * HDIM + dt * 16 + grp * 4] = pk;
        }
    }
}

extern "C" void kernel_launch(void* const* d_in, const int* in_sizes, int n_in,
                              void* d_out, int out_size, void* d_ws, size_t ws_size,
                              hipStream_t stream) {
    int iX, iWq, ibq, iWk, ibk, iWv, ibv, iWo, ibo;
    if (in_sizes[0] == MTOT * HID) {
        iX = 0; iWq = 1; ibq = 2; iWk = 3; ibk = 4; iWv = 5; ibv = 6; iWo = 7; ibo = 8;
    } else {
        iWk = 0; iWo = 1; iWq = 2; iWv = 3; ibk = 4; ibo = 5; ibq = 6; ibv = 7; iX = 8;
    }
    const float* X  = (const float*)d_in[iX];
    const float* Wq = (const float*)d_in[iWq];
    const float* bq = (const float*)d_in[ibq];
    const float* Wk = (const float*)d_in[iWk];
    const float* bk = (const float*)d_in[ibk];
    const float* Wv = (const float*)d_in[iWv];
    const float* bv = (const float*)d_in[ibv];
    const float* Wo = (const float*)d_in[iWo];
    const float* bo = (const float*)d_in[ibo];
    float* out = (float*)d_out;

    unsigned short* ws = (unsigned short*)d_ws;
    const size_t T = (size_t)MTOT * HID;
    unsigned short* qw  = ws;                  // Q  [b][h][s][d] (pre-scaled)
    unsigned short* kfr = ws + T;              // K  fragment-major per (b,h)
    unsigned short* vfr = ws + 2 * T;          // V  fragment-major per (b,h)
    unsigned short* x2  = ws + 3 * T;          // attn out [b][s][hid]
    unsigned short* Xb  = ws + 4 * T;
    unsigned short* Wqb = Xb + T;
    unsigned short* Wkb = Wqb + (size_t)HID * HID;
    unsigned short* Wvb = Wkb + (size_t)HID * HID;
    unsigned short* Wob = Wvb + (size_t)HID * HID;

    cvt5<<<dim3(4096, 5), 256, 0, stream>>>(X, Wq, Wk, Wv, Wo, Xb);
    // fused QKV: X staged once, 24 MFMA per barrier-pair
    gemm_qkv<<<dim3(64, 8), 256, 0, stream>>>(
        Xb, Wqb, Wkb, Wvb, bq, bk, bv, qw);
    attn_kernel<<<dim3(2048), 64, 0, stream>>>(qw, kfr, vfr, x2);
    // out-proj: 64x128 -> 512 wg, 8 MFMA/iter
    gemm_out<64, 128><<<dim3(64, 8), 256, 0, stream>>>(x2, Wob, bo, out);
}